// Round 9
// baseline (378.654 us; speedup 1.0000x reference)
//
#include <hip/hip_runtime.h>

#define IN_F 4096
#define OUT_F 11008
#define NCLUST 16
#define TOPK 1024
#define MAGIC 0x5D3A7F21u

__device__ __forceinline__ float dot4(float4 a, float4 b) {
    return a.x * b.x + a.y * b.y + a.z * b.z + a.w * b.w;
}
__device__ __forceinline__ float wredsum(float v) {
    for (int o = 32; o > 0; o >>= 1) v += __shfl_down(v, o, 64);
    return v;
}

// One fused kernel. Block 0: select -> publish xm + flag (R7's validated
// protocol). Blocks 1..2752: prefetch their 4 W rows into registers FIRST,
// then wait for the flag, then one dot+reduce+store per wave.
__global__ __launch_bounds__(256, 5) void fused_kernel(
    const float* __restrict__ x,
    const float* __restrict__ W,
    const float* __restrict__ bias,
    const float* __restrict__ centers,
    float* __restrict__ out,
    float* __restrict__ xm_ws)          // d_ws: xm[4096] + flag
{
    const int tid  = threadIdx.x;
    const int lane = tid & 63;
    const int wid  = tid >> 6;
    const int bid  = blockIdx.x;

    __shared__ __align__(16) float sxm[IN_F];     // block0: e; consumers: xm
    __shared__ unsigned int hist[4][256];
    __shared__ float swred[4];
    __shared__ float sdot[NCLUST], scsq[NCLUST];
    __shared__ unsigned int wtot4[4], weq[4];
    __shared__ unsigned int sprefix, sKrem, sG;
    __shared__ int sci;

    unsigned int* flag = (unsigned int*)(xm_ws + IN_F);
    float4* sxm4 = (float4*)sxm;

    if (bid == 0) {
        // ==================== SELECT (256 threads, 4 waves) ====================
        float4 xq0 = ((const float4*)x)[tid * 4 + 0];
        float4 xq1 = ((const float4*)x)[tid * 4 + 1];
        float4 xq2 = ((const float4*)x)[tid * 4 + 2];
        float4 xq3 = ((const float4*)x)[tid * 4 + 3];

        // e = exp(|x|)  (|x| <= ~6 for N(0,1): fp32-safe without max-pass)
        float e[16];
        e[0]=expf(fabsf(xq0.x)); e[1]=expf(fabsf(xq0.y)); e[2]=expf(fabsf(xq0.z)); e[3]=expf(fabsf(xq0.w));
        e[4]=expf(fabsf(xq1.x)); e[5]=expf(fabsf(xq1.y)); e[6]=expf(fabsf(xq1.z)); e[7]=expf(fabsf(xq1.w));
        e[8]=expf(fabsf(xq2.x)); e[9]=expf(fabsf(xq2.y)); e[10]=expf(fabsf(xq2.z)); e[11]=expf(fabsf(xq2.w));
        e[12]=expf(fabsf(xq3.x)); e[13]=expf(fabsf(xq3.y)); e[14]=expf(fabsf(xq3.z)); e[15]=expf(fabsf(xq3.w));
        {
            sxm4[tid*4+0] = make_float4(e[0],e[1],e[2],e[3]);
            sxm4[tid*4+1] = make_float4(e[4],e[5],e[6],e[7]);
            sxm4[tid*4+2] = make_float4(e[8],e[9],e[10],e[11]);
            sxm4[tid*4+3] = make_float4(e[12],e[13],e[14],e[15]);
            float s = 0.0f;
            #pragma unroll
            for (int k = 0; k < 16; ++k) s += e[k];
            s = wredsum(s);
            if (lane == 0) swred[wid] = s;
            unsigned int* hflat = &hist[0][0];
            hflat[tid] = 0u; hflat[tid+256] = 0u; hflat[tid+512] = 0u; hflat[tid+768] = 0u;
            if (tid == 0) { sprefix = 0u; sKrem = TOPK; sG = 0u; }
        }
        __syncthreads();
        const float S = swred[0] + swred[1] + swred[2] + swred[3];

        // per-cluster dot(c,e), sum(c^2): wave w -> clusters 4w..4w+3
        {
            const float*  cb  = centers + (size_t)(4 * wid) * IN_F;
            const float4* c0p = (const float4*)(cb);
            const float4* c1p = (const float4*)(cb + IN_F);
            const float4* c2p = (const float4*)(cb + 2 * IN_F);
            const float4* c3p = (const float4*)(cb + 3 * IN_F);
            float d0=0,d1=0,d2=0,d3=0,q0=0,q1=0,q2=0,q3=0;
            #pragma unroll
            for (int j = 0; j < 16; ++j) {
                const int idx = j * 64 + lane;
                float4 ev = sxm4[idx];
                float4 a = c0p[idx], b = c1p[idx], c = c2p[idx], d = c3p[idx];
                d0 += dot4(a, ev); q0 += dot4(a, a);
                d1 += dot4(b, ev); q1 += dot4(b, b);
                d2 += dot4(c, ev); q2 += dot4(c, c);
                d3 += dot4(d, ev); q3 += dot4(d, d);
            }
            d0 = wredsum(d0); d1 = wredsum(d1); d2 = wredsum(d2); d3 = wredsum(d3);
            q0 = wredsum(q0); q1 = wredsum(q1); q2 = wredsum(q2); q3 = wredsum(q3);
            if (lane == 0) {
                sdot[4*wid+0]=d0; sdot[4*wid+1]=d1; sdot[4*wid+2]=d2; sdot[4*wid+3]=d3;
                scsq[4*wid+0]=q0; scsq[4*wid+1]=q1; scsq[4*wid+2]=q2; scsq[4*wid+3]=q3;
            }
        }
        __syncthreads();

        // argmin_cl [ sum(c^2) - (2/S) dot(c,e) ]  (strict <: first-min-index)
        if (wid == 0) {
            float v = (lane < NCLUST) ? (scsq[lane] - (2.0f / S) * sdot[lane]) : 3.0e38f;
            int bi = lane;
            for (int off = 8; off > 0; off >>= 1) {
                float ov = __shfl_down(v, off, 64);
                int   oi = __shfl_down(bi, off, 64);
                if (ov < v) { v = ov; bi = oi; }
            }
            if (lane == 0) sci = bi;
        }
        __syncthreads();

        // chosen center (positive floats: uint compare == float compare)
        const float4* cc4 = (const float4*)(centers + (size_t)sci * IN_F);
        float4 c0 = cc4[tid*4+0], c1 = cc4[tid*4+1], c2 = cc4[tid*4+2], c3 = cc4[tid*4+3];
        unsigned int cv[16];
        cv[0]=__float_as_uint(c0.x); cv[1]=__float_as_uint(c0.y); cv[2]=__float_as_uint(c0.z); cv[3]=__float_as_uint(c0.w);
        cv[4]=__float_as_uint(c1.x); cv[5]=__float_as_uint(c1.y); cv[6]=__float_as_uint(c1.z); cv[7]=__float_as_uint(c1.w);
        cv[8]=__float_as_uint(c2.x); cv[9]=__float_as_uint(c2.y); cv[10]=__float_as_uint(c2.z); cv[11]=__float_as_uint(c2.w);
        cv[12]=__float_as_uint(c3.x); cv[13]=__float_as_uint(c3.y); cv[14]=__float_as_uint(c3.z); cv[15]=__float_as_uint(c3.w);

        // ---- 4-pass radix select for the 1024th-largest value ----
        for (int pass = 0; pass < 4; ++pass) {
            const int shift = 24 - 8 * pass;
            const unsigned int pfx  = sprefix;
            const unsigned int krem = sKrem;
            unsigned int* hp = hist[wid];
            #pragma unroll
            for (int k = 0; k < 16; ++k) {
                unsigned int u = cv[k];
                bool cand = (pass == 0) || ((u >> (shift + 8)) == pfx);
                if (cand) atomicAdd(&hp[(u >> shift) & 255u], 1u);
            }
            __syncthreads();
            unsigned int h, s;
            {
                const unsigned int b = tid;
                h = hist[0][b] + hist[1][b] + hist[2][b] + hist[3][b];
                hist[0][b] = 0u; hist[1][b] = 0u; hist[2][b] = 0u; hist[3][b] = 0u;
                s = h;  // suffix-inclusive scan within wave (bin order)
                for (int off = 1; off < 64; off <<= 1) {
                    unsigned int v2 = __shfl_down(s, off, 64);
                    if (lane + off < 64) s += v2;
                }
                if (lane == 0) wtot4[wid] = s;
            }
            __syncthreads();
            {
                unsigned int add = 0;
                #pragma unroll
                for (int w2 = 0; w2 < 4; ++w2) if (w2 > wid) add += wtot4[w2];
                unsigned int incl = s + add;       // # values in bins >= tid
                unsigned int excl = incl - h;      // # values in bins >  tid
                if (excl < krem && krem <= incl) { // exactly one thread
                    sprefix = (pfx << 8) | (unsigned int)tid;
                    sKrem   = krem - excl;
                }
            }
            __syncthreads();
        }
        const unsigned int T = sprefix;

        // ---- tie bookkeeping (stable: first (TOPK-G) equals in index order) ----
        unsigned int gt = 0, eq = 0;
        #pragma unroll
        for (int k = 0; k < 16; ++k) {
            gt += (cv[k] > T) ? 1u : 0u;
            eq += (cv[k] == T) ? 1u : 0u;
        }
        {
            unsigned int g = gt;
            for (int o = 32; o > 0; o >>= 1) g += __shfl_down(g, o, 64);
            if (lane == 0) atomicAdd(&sG, g);
        }
        unsigned int p = eq;
        for (int off = 1; off < 64; off <<= 1) {
            unsigned int v2 = __shfl_up(p, off, 64);
            if (lane >= off) p += v2;
        }
        if (lane == 63) weq[wid] = p;
        __syncthreads();
        unsigned int base = p - eq;
        #pragma unroll
        for (int w2 = 0; w2 < 4; ++w2) if (w2 < wid) base += weq[w2];
        const unsigned int needEq = TOPK - sG;

        // ---- emit masked x DIRECTLY to global xm, then publish flag ----
        {
            float xs[16] = {xq0.x,xq0.y,xq0.z,xq0.w, xq1.x,xq1.y,xq1.z,xq1.w,
                            xq2.x,xq2.y,xq2.z,xq2.w, xq3.x,xq3.y,xq3.z,xq3.w};
            float os[16];
            unsigned int r = 0;
            #pragma unroll
            for (int k = 0; k < 16; ++k) {
                bool sel = (cv[k] > T) || ((cv[k] == T) && (base + r < needEq));
                os[k] = sel ? xs[k] : 0.0f;
                r += (cv[k] == T) ? 1u : 0u;
            }
            float4* xw = (float4*)xm_ws;
            xw[tid*4+0] = make_float4(os[0],os[1],os[2],os[3]);
            xw[tid*4+1] = make_float4(os[4],os[5],os[6],os[7]);
            xw[tid*4+2] = make_float4(os[8],os[9],os[10],os[11]);
            xw[tid*4+3] = make_float4(os[12],os[13],os[14],os[15]);
        }
        __threadfence();
        __syncthreads();
        if (tid == 0)
            __hip_atomic_store(flag, MAGIC, __ATOMIC_RELEASE, __HIP_MEMORY_SCOPE_AGENT);
        return;
    }

    // ==================== CONSUMER: 4 rows, register-prefetched ====================
    const int row = (bid - 1) * 4 + wid;
    const float4* wr = (const float4*)(W + (size_t)row * IN_F);
    // issue the whole row (16 dwordx4) immediately — in flight during the wait
    float4 w0  = wr[0*64 + lane],  w1  = wr[1*64 + lane];
    float4 w2  = wr[2*64 + lane],  w3  = wr[3*64 + lane];
    float4 w4  = wr[4*64 + lane],  w5  = wr[5*64 + lane];
    float4 w6  = wr[6*64 + lane],  w7  = wr[7*64 + lane];
    float4 w8  = wr[8*64 + lane],  w9  = wr[9*64 + lane];
    float4 w10 = wr[10*64 + lane], w11 = wr[11*64 + lane];
    float4 w12 = wr[12*64 + lane], w13 = wr[13*64 + lane];
    float4 w14 = wr[14*64 + lane], w15 = wr[15*64 + lane];
    const float bv = bias[row];
    asm volatile("" ::: "memory");   // pin the prefetch before the spin

    if (tid == 0) {
        while (__hip_atomic_load(flag, __ATOMIC_ACQUIRE,
                                 __HIP_MEMORY_SCOPE_AGENT) != MAGIC)
            __builtin_amdgcn_s_sleep(8);
    }
    __syncthreads();
    __threadfence();

    // stage xm (16 KB) into LDS
    {
        const float4* xg = (const float4*)xm_ws;
        sxm4[tid*4+0] = xg[tid*4+0];
        sxm4[tid*4+1] = xg[tid*4+1];
        sxm4[tid*4+2] = xg[tid*4+2];
        sxm4[tid*4+3] = xg[tid*4+3];
    }
    __syncthreads();

    float acc = dot4(w0,  sxm4[0*64 + lane])  + dot4(w1,  sxm4[1*64 + lane])
              + dot4(w2,  sxm4[2*64 + lane])  + dot4(w3,  sxm4[3*64 + lane])
              + dot4(w4,  sxm4[4*64 + lane])  + dot4(w5,  sxm4[5*64 + lane])
              + dot4(w6,  sxm4[6*64 + lane])  + dot4(w7,  sxm4[7*64 + lane])
              + dot4(w8,  sxm4[8*64 + lane])  + dot4(w9,  sxm4[9*64 + lane])
              + dot4(w10, sxm4[10*64 + lane]) + dot4(w11, sxm4[11*64 + lane])
              + dot4(w12, sxm4[12*64 + lane]) + dot4(w13, sxm4[13*64 + lane])
              + dot4(w14, sxm4[14*64 + lane]) + dot4(w15, sxm4[15*64 + lane]);
    acc = wredsum(acc);
    if (lane == 0) out[row] = acc + bv;
}

extern "C" void kernel_launch(void* const* d_in, const int* in_sizes, int n_in,
                              void* d_out, int out_size, void* d_ws, size_t ws_size,
                              hipStream_t stream) {
    const float* x       = (const float*)d_in[0];  // [1,1,4096]
    const float* weight  = (const float*)d_in[1];  // [11008,4096]
    const float* bias    = (const float*)d_in[2];  // [11008]
    const float* centers = (const float*)d_in[3];  // [16,4096]
    float* out = (float*)d_out;                    // [11008]
    float* xm  = (float*)d_ws;                     // xm[4096] + flag

    fused_kernel<<<1 + OUT_F / 4, 256, 0, stream>>>(x, weight, bias, centers, out, xm);
}

// Round 10
// 98.933 us; speedup vs baseline: 3.8274x; 3.8274x over previous
//
#include <hip/hip_runtime.h>

#define IN_F 4096
#define OUT_F 11008
#define NCLUST 16
#define TOPK 1024
#define NW 16
#define ROWS_PB 43          // 256 blocks * 43 rows = 11008
#define MAGIC 0x5D3A7F21u

typedef float f4 __attribute__((ext_vector_type(4)));

__device__ __forceinline__ float dot4(float4 a, float4 b) {
    return a.x * b.x + a.y * b.y + a.z * b.z + a.w * b.w;
}
__device__ __forceinline__ float wredsum(float v) {
    for (int o = 32; o > 0; o >>= 1) v += __shfl_down(v, o, 64);
    return v;
}
__device__ __forceinline__ float dotf4(f4 a, f4 b) {
    return a[0] * b[0] + a[1] * b[1] + a[2] * b[2] + a[3] * b[3];
}

// Fused kernel. Block 0: select -> publish xm + flag (R7-validated protocol).
// Blocks 1..255: inline-asm prefetch of first row into 64 VGPRs (cannot be
// sunk by the compiler), spin, then stream 43 rows (R8's proven engine).
__global__ __launch_bounds__(1024, 4) void fused_kernel(
    const float* __restrict__ x,
    const float* __restrict__ W,
    const float* __restrict__ bias,
    const float* __restrict__ centers,
    float* __restrict__ out,
    float* __restrict__ xm_ws)          // d_ws: xm[4096] + flag
{
    const int tid  = threadIdx.x;
    const int lane = tid & 63;
    const int wid  = tid >> 6;
    const int bid  = blockIdx.x;
    const int rbase = bid * ROWS_PB;

    __shared__ __align__(16) float sxm[IN_F];     // block0: e; all: masked x
    __shared__ unsigned int hist[NW * 256];       // select only (block 0)
    __shared__ float swred[NW];
    __shared__ float sdot[NCLUST], scsq[NCLUST];
    __shared__ unsigned int wtot4[4], weq[NW];
    __shared__ unsigned int sprefix, sKrem, sG;
    __shared__ int sci;

    unsigned int* flag = (unsigned int*)(xm_ws + IN_F);
    f4* sxm4 = (f4*)sxm;

    if (bid == 0) {
        // ==================== SELECT (16 waves; R8-A structure) ====================
        float4 xv = ((const float4*)x)[tid];
        float e0 = expf(fabsf(xv.x)), e1 = expf(fabsf(xv.y));
        float e2 = expf(fabsf(xv.z)), e3 = expf(fabsf(xv.w));
        ((float4*)sxm)[tid] = make_float4(e0, e1, e2, e3);
        {
            float s = wredsum(e0 + e1 + e2 + e3);
            if (lane == 0) swred[wid] = s;
            hist[tid] = 0u; hist[tid + 1024] = 0u;
            hist[tid + 2048] = 0u; hist[tid + 3072] = 0u;
            if (tid == 0) { sprefix = 0u; sKrem = TOPK; sG = 0u; }
        }
        __syncthreads();
        float S = 0.0f;
        #pragma unroll
        for (int k = 0; k < NW; ++k) S += swred[k];

        // per-cluster dot(c,e), sum(c^2): wave w -> cluster w
        {
            const float4* cp = (const float4*)(centers + (size_t)wid * IN_F);
            const float4* a4 = (const float4*)sxm;
            float dt = 0.0f, cq = 0.0f;
            #pragma unroll
            for (int j = 0; j < 16; ++j) {
                float4 c = cp[j * 64 + lane];
                float4 a = a4[j * 64 + lane];
                dt += dot4(c, a);
                cq += dot4(c, c);
            }
            dt = wredsum(dt);
            cq = wredsum(cq);
            if (lane == 0) { sdot[wid] = dt; scsq[wid] = cq; }
        }
        __syncthreads();

        // argmin_cl [ sum(c^2) - (2/S) dot(c,e) ]  (strict <: first-min-index)
        if (wid == 0) {
            float v = (lane < NCLUST) ? (scsq[lane] - (2.0f / S) * sdot[lane]) : 3.0e38f;
            int bi = lane;
            for (int off = 8; off > 0; off >>= 1) {
                float ov = __shfl_down(v, off, 64);
                int   oi = __shfl_down(bi, off, 64);
                if (ov < v) { v = ov; bi = oi; }
            }
            if (lane == 0) sci = bi;
        }
        __syncthreads();

        // chosen center (positive floats: uint compare == float compare)
        unsigned int cv[4];
        {
            float4 c = ((const float4*)(centers + (size_t)sci * IN_F))[tid];
            cv[0] = __float_as_uint(c.x); cv[1] = __float_as_uint(c.y);
            cv[2] = __float_as_uint(c.z); cv[3] = __float_as_uint(c.w);
        }

        // ---- 4-pass radix select for the 1024th-largest value ----
        for (int pass = 0; pass < 4; ++pass) {
            const int shift = 24 - 8 * pass;
            const unsigned int pfx  = sprefix;
            const unsigned int krem = sKrem;
            unsigned int* hp = &hist[wid * 256];
            #pragma unroll
            for (int j = 0; j < 4; ++j) {
                unsigned int u = cv[j];
                bool cand = (pass == 0) || ((u >> (shift + 8)) == pfx);
                if (cand) atomicAdd(&hp[(u >> shift) & 255u], 1u);
            }
            __syncthreads();
            unsigned int h = 0, s = 0;
            if (tid < 256) {
                #pragma unroll
                for (int w = 0; w < NW; ++w) { h += hist[w * 256 + tid]; hist[w * 256 + tid] = 0u; }
                s = h;  // suffix-inclusive scan within wave (bin order)
                for (int off = 1; off < 64; off <<= 1) {
                    unsigned int v2 = __shfl_down(s, off, 64);
                    if (lane + off < 64) s += v2;
                }
                if (lane == 0) wtot4[wid] = s;
            }
            __syncthreads();
            if (tid < 256) {
                unsigned int add = 0;
                #pragma unroll
                for (int w2 = 0; w2 < 4; ++w2) if (w2 > wid) add += wtot4[w2];
                unsigned int incl = s + add;       // # values in bins >= tid
                unsigned int excl = incl - h;      // # values in bins >  tid
                if (excl < krem && krem <= incl) { // exactly one thread
                    sprefix = (pfx << 8) | (unsigned int)tid;
                    sKrem   = krem - excl;
                }
            }
            __syncthreads();
        }
        const unsigned int T = sprefix;

        // ---- tie bookkeeping (stable: first (TOPK-G) equals in index order) ----
        unsigned int gt = 0, eq = 0;
        #pragma unroll
        for (int j = 0; j < 4; ++j) {
            gt += (cv[j] > T) ? 1u : 0u;
            eq += (cv[j] == T) ? 1u : 0u;
        }
        {
            unsigned int g = gt;
            for (int o = 32; o > 0; o >>= 1) g += __shfl_down(g, o, 64);
            if (lane == 0) atomicAdd(&sG, g);
        }
        unsigned int p = eq;
        for (int off = 1; off < 64; off <<= 1) {
            unsigned int v2 = __shfl_up(p, off, 64);
            if (lane >= off) p += v2;
        }
        if (lane == 63) weq[wid] = p;
        __syncthreads();
        unsigned int base = p - eq;
        #pragma unroll
        for (int w = 0; w < NW; ++w) if (w < wid) base += weq[w];
        const unsigned int needEq = TOPK - sG;

        // ---- emit masked x: global xm + LDS sxm, then publish flag ----
        {
            unsigned int r = 0;
            float4 o;
            o.x = ((cv[0] > T) || ((cv[0] == T) && (base + r < needEq))) ? xv.x : 0.0f; r += (cv[0] == T);
            o.y = ((cv[1] > T) || ((cv[1] == T) && (base + r < needEq))) ? xv.y : 0.0f; r += (cv[1] == T);
            o.z = ((cv[2] > T) || ((cv[2] == T) && (base + r < needEq))) ? xv.z : 0.0f; r += (cv[2] == T);
            o.w = ((cv[3] > T) || ((cv[3] == T) && (base + r < needEq))) ? xv.w : 0.0f;
            ((float4*)sxm)[tid] = o;
            ((float4*)xm_ws)[tid] = o;
        }
        __threadfence();
        __syncthreads();
        if (tid == 0)
            __hip_atomic_store(flag, MAGIC, __ATOMIC_RELEASE, __HIP_MEMORY_SCOPE_AGENT);

        // ---- stream this block's 43 rows (normal engine) ----
        const f4* sx = (const f4*)sxm;
        for (int r = wid; r < ROWS_PB; r += NW) {
            const int row = rbase + r;
            const f4* wr = (const f4*)(W + (size_t)row * IN_F);
            float acc = 0.0f;
            #pragma unroll
            for (int j = 0; j < 16; ++j) {
                f4 wv = wr[j * 64 + lane];
                f4 xj = sx[j * 64 + lane];
                acc += dotf4(wv, xj);
            }
            acc = wredsum(acc);
            if (lane == 0) out[row] = acc + bias[row];
        }
        return;
    }

    // ==================== CONSUMERS ====================
    // Inline-asm prefetch of first row (16 KB/wave) — cannot be sunk/spilled.
    const int r0 = rbase + wid;
    const float* rp0 = W + (size_t)r0 * IN_F + lane * 4;   // + j*1024 bytes, j=0..3
    const float* rp1 = rp0 + 1024;                         // +4096 B
    const float* rp2 = rp0 + 2048;
    const float* rp3 = rp0 + 3072;
    f4 w0, w1, w2, w3, w4, w5, w6, w7, w8, w9, w10, w11, w12, w13, w14, w15;
#define PF(REG, BASE, OFF) \
    asm volatile("global_load_dwordx4 %0, %1, off offset:" #OFF \
                 : "=v"(REG) : "v"(BASE) : "memory")
    PF(w0,  rp0, 0); PF(w1,  rp0, 1024); PF(w2,  rp0, 2048); PF(w3,  rp0, 3072);
    PF(w4,  rp1, 0); PF(w5,  rp1, 1024); PF(w6,  rp1, 2048); PF(w7,  rp1, 3072);
    PF(w8,  rp2, 0); PF(w9,  rp2, 1024); PF(w10, rp2, 2048); PF(w11, rp2, 3072);
    PF(w12, rp3, 0); PF(w13, rp3, 1024); PF(w14, rp3, 2048); PF(w15, rp3, 3072);
#undef PF

    // spin until the mask is published (prefetch stays in flight)
    if (tid == 0) {
        while (__hip_atomic_load(flag, __ATOMIC_ACQUIRE,
                                 __HIP_MEMORY_SCOPE_AGENT) != MAGIC)
            __builtin_amdgcn_s_sleep(8);
    }
    __syncthreads();
    __threadfence();

    // stage xm into LDS (1024 threads x 1 float4 = 16 KB)
    sxm4[tid] = ((const f4*)xm_ws)[tid];
    __syncthreads();

    // consume prefetched row 0 (wait for asm loads; block FMA hoist)
    asm volatile("s_waitcnt vmcnt(0)" ::: "memory");
    __builtin_amdgcn_sched_barrier(0);
    const f4* sx = (const f4*)sxm;
    {
        float acc = 0.0f;
        acc += dotf4(w0,  sx[0 * 64 + lane]);
        acc += dotf4(w1,  sx[1 * 64 + lane]);
        acc += dotf4(w2,  sx[2 * 64 + lane]);
        acc += dotf4(w3,  sx[3 * 64 + lane]);
        acc += dotf4(w4,  sx[4 * 64 + lane]);
        acc += dotf4(w5,  sx[5 * 64 + lane]);
        acc += dotf4(w6,  sx[6 * 64 + lane]);
        acc += dotf4(w7,  sx[7 * 64 + lane]);
        acc += dotf4(w8,  sx[8 * 64 + lane]);
        acc += dotf4(w9,  sx[9 * 64 + lane]);
        acc += dotf4(w10, sx[10 * 64 + lane]);
        acc += dotf4(w11, sx[11 * 64 + lane]);
        acc += dotf4(w12, sx[12 * 64 + lane]);
        acc += dotf4(w13, sx[13 * 64 + lane]);
        acc += dotf4(w14, sx[14 * 64 + lane]);
        acc += dotf4(w15, sx[15 * 64 + lane]);
        acc = wredsum(acc);
        if (lane == 0) out[r0] = acc + bias[r0];
    }

    // remaining rows: plain streaming (R8 engine)
    for (int r = wid + NW; r < ROWS_PB; r += NW) {
        const int row = rbase + r;
        const f4* wr = (const f4*)(W + (size_t)row * IN_F);
        float acc = 0.0f;
        #pragma unroll
        for (int j = 0; j < 16; ++j) {
            f4 wv = wr[j * 64 + lane];
            f4 xj = sx[j * 64 + lane];
            acc += dotf4(wv, xj);
        }
        acc = wredsum(acc);
        if (lane == 0) out[row] = acc + bias[row];
    }
}

extern "C" void kernel_launch(void* const* d_in, const int* in_sizes, int n_in,
                              void* d_out, int out_size, void* d_ws, size_t ws_size,
                              hipStream_t stream) {
    const float* x       = (const float*)d_in[0];  // [1,1,4096]
    const float* weight  = (const float*)d_in[1];  // [11008,4096]
    const float* bias    = (const float*)d_in[2];  // [11008]
    const float* centers = (const float*)d_in[3];  // [16,4096]
    float* out = (float*)d_out;                    // [11008]
    float* xm  = (float*)d_ws;                     // xm[4096] + flag

    fused_kernel<<<256, 1024, 0, stream>>>(x, weight, bias, centers, out, xm);
}